// Round 6
// baseline (852.064 us; speedup 1.0000x reference)
//
#include <hip/hip_runtime.h>
#include <hip/hip_bf16.h>

// LightGCN: 3 layers of SpMM on 200000x64 embeddings, 3.2M edges.
// R5: scatter writes were HBM-RMW-bound (masked partial-line evictions,
// 198MB @ ~860GB/s). Fix: window the scatter by PHYSICAL XCC_ID (not
// blockIdx%8 heuristic) via per-window work queues + stealing, and use
// nontemporal loads for the edge stream so it can't evict the ~3.2MB
// write window from the 4MB per-XCD L2. bf16 embeddings kept (R4 win).

constexpr int NUM_USERS = 100000;
constexpr int NUM_ITEMS = 100000;
constexpr int N_NODES   = NUM_USERS + NUM_ITEMS;   // 200000
constexpr int EMB       = 64;
constexpr int N_EDGES   = 3200000;

constexpr int SCAN_BLOCK = 256;
constexpr int SCAN_ELEMS = 1024;                   // 4 per thread
constexpr int NUM_SCAN_BLOCKS = (N_NODES + SCAN_ELEMS - 1) / SCAN_ELEMS; // 196
constexpr int NQ    = 8;                           // one window per XCD
constexpr int WIN   = (N_NODES + NQ - 1) / NQ;     // 25000 rows per window
constexpr int CHUNK = 16384;                       // edges per work-queue grab

// ---------------- bf16 helpers ----------------

__device__ __forceinline__ float bfl(unsigned u) { return __uint_as_float(u << 16); }
__device__ __forceinline__ float bfh(unsigned u) { return __uint_as_float(u & 0xFFFF0000u); }
__device__ __forceinline__ unsigned f2bf(float f) {          // RNE
    unsigned u = __float_as_uint(f);
    return (u + 0x7FFFu + ((u >> 16) & 1u)) >> 16;
}
__device__ __forceinline__ unsigned pk(float lo, float hi) {
    return f2bf(lo) | (f2bf(hi) << 16);
}

__device__ __forceinline__ int get_xcd() {
    unsigned x;
    asm volatile("s_getreg_b32 %0, hwreg(HW_REG_XCC_ID)" : "=s"(x));
    return (int)(x & 7);
}

// concat(user,item) -> bf16 rows. i = uint4 index (16B out, 32B in).
__global__ void concat_bf16(const float4* __restrict__ u, const float4* __restrict__ it,
                            uint4* __restrict__ ebuf) {
    int i = blockIdx.x * blockDim.x + threadIdx.x;
    if (i >= N_NODES * 8) return;
    const float4* s = (i < NUM_USERS * 8) ? (u + 2 * (size_t)i)
                                          : (it + 2 * ((size_t)i - (size_t)NUM_USERS * 8));
    float4 f0 = s[0], f1 = s[1];
    uint4 o;
    o.x = pk(f0.x, f0.y); o.y = pk(f0.z, f0.w);
    o.z = pk(f1.x, f1.y); o.w = pk(f1.z, f1.w);
    ebuf[i] = o;
}

// ---------------- CSR build ----------------

__global__ void histogram(const int* __restrict__ row, int* __restrict__ cnt) {
    int e = blockIdx.x * blockDim.x + threadIdx.x;
    if (e >= N_EDGES) return;
    atomicAdd(&cnt[row[e]], 1);
}

__global__ void scan_reduce(const int* __restrict__ cnt, int* __restrict__ partials) {
    __shared__ int lds[SCAN_BLOCK];
    int b = blockIdx.x, t = threadIdx.x;
    int base = b * SCAN_ELEMS + t * 4;
    int s = 0;
#pragma unroll
    for (int k = 0; k < 4; ++k) {
        int i = base + k;
        if (i < N_NODES) s += cnt[i];
    }
    lds[t] = s;
    __syncthreads();
    for (int off = SCAN_BLOCK / 2; off > 0; off >>= 1) {
        if (t < off) lds[t] += lds[t + off];
        __syncthreads();
    }
    if (t == 0) partials[b] = lds[0];
}

__global__ void scan_partials(int* partials) {
    __shared__ int lds[SCAN_BLOCK];
    int t = threadIdx.x;
    int v = (t < NUM_SCAN_BLOCKS) ? partials[t] : 0;
    lds[t] = v;
    __syncthreads();
    for (int off = 1; off < SCAN_BLOCK; off <<= 1) {
        int x = (t >= off) ? lds[t - off] : 0;
        __syncthreads();
        lds[t] += x;
        __syncthreads();
    }
    if (t < NUM_SCAN_BLOCKS) partials[t] = lds[t] - v;   // exclusive
}

__global__ void scan_final(const int* __restrict__ cnt, const int* __restrict__ partials,
                           int* __restrict__ row_start, int* __restrict__ cursor) {
    __shared__ int lds[SCAN_BLOCK];
    int b = blockIdx.x, t = threadIdx.x;
    int base = b * SCAN_ELEMS + t * 4;
    int v[4], pre[4];
    int s = 0;
#pragma unroll
    for (int k = 0; k < 4; ++k) {
        int i = base + k;
        v[k] = (i < N_NODES) ? cnt[i] : 0;
        pre[k] = s;
        s += v[k];
    }
    lds[t] = s;
    __syncthreads();
    for (int off = 1; off < SCAN_BLOCK; off <<= 1) {
        int x = (t >= off) ? lds[t - off] : 0;
        __syncthreads();
        lds[t] += x;
        __syncthreads();
    }
    int thread_excl = lds[t] - s;
    int blockbase = partials[b];
#pragma unroll
    for (int k = 0; k < 4; ++k) {
        int i = base + k;
        if (i < N_NODES) {
            int val = blockbase + thread_excl + pre[k];
            row_start[i] = val;
            cursor[i]    = val;
        }
    }
    if (b == 0 && t == 0) row_start[N_NODES] = N_EDGES;
}

// windowed scatter: block drains the work queue of its PHYSICAL XCD first,
// then steals from the others (correct for any block->XCD mapping).
__global__ void scatter_win(const int* __restrict__ row, const int* __restrict__ col,
                            const float* __restrict__ w,
                            int* __restrict__ cursor, int2* __restrict__ sorted,
                            int* __restrict__ wq) {
    __shared__ int cs;
    int my = get_xcd();
    for (int k = 0; k < NQ; ++k) {
        int q = (my + k) & (NQ - 1);
        int lo = q * WIN;
        int hi = lo + WIN; if (hi > N_NODES) hi = N_NODES;
        while (true) {
            if (threadIdx.x == 0) cs = atomicAdd(&wq[q], CHUNK);
            __syncthreads();
            int c = cs;
            __syncthreads();
            if (c >= N_EDGES) break;
            int e_end = c + CHUNK; if (e_end > N_EDGES) e_end = N_EDGES;
            for (int e = c + (int)threadIdx.x; e < e_end; e += (int)blockDim.x) {
                int r = __builtin_nontemporal_load(&row[e]);
                if (r >= lo && r < hi) {
                    int   cc = __builtin_nontemporal_load(&col[e]);
                    float ww = __builtin_nontemporal_load(&w[e]);
                    int pos = atomicAdd(&cursor[r], 1);
                    sorted[pos] = make_int2(cc, __float_as_int(ww));
                }
            }
        }
    }
}

// ---------------- SpMM: bf16 gather, 8-lane groups, 16 edges in flight ----------------

template<bool FIRST, bool WRITE_Y>
__global__ __launch_bounds__(256) void spmm_bf16(
    const int* __restrict__ row_start, const int2* __restrict__ sorted,
    const uint4* __restrict__ src,     // bf16 rows: 8 x uint4 per row
    uint4* __restrict__ y,             // bf16 rows out
    float4* __restrict__ acc)          // f32 accumulator (d_out)
{
    int lane = threadIdx.x & 63;
    int r = blockIdx.x * 4 + (threadIdx.x >> 6);
    if (r >= N_NODES) return;
    int g = lane >> 3;        // edge group 0..7
    int s = lane & 7;         // 16B slot within row (8 bf16)
    int s0 = row_start[r];
    int s1 = row_start[r + 1];

    float a0 = 0.f, a1 = 0.f, a2 = 0.f, a3 = 0.f;
    float a4 = 0.f, a5 = 0.f, a6 = 0.f, a7 = 0.f;

    for (int base = s0; base < s1; base += 16) {
        int i0 = base + g;
        int i1 = base + 8 + g;
        if (i0 < s1) {
            int ex = __builtin_nontemporal_load(&sorted[i0].x);
            int ey = __builtin_nontemporal_load(&sorted[i0].y);
            float wt = __int_as_float(ey);
            uint4 v = src[(size_t)ex * 8 + s];
            a0 = fmaf(wt, bfl(v.x), a0); a1 = fmaf(wt, bfh(v.x), a1);
            a2 = fmaf(wt, bfl(v.y), a2); a3 = fmaf(wt, bfh(v.y), a3);
            a4 = fmaf(wt, bfl(v.z), a4); a5 = fmaf(wt, bfh(v.z), a5);
            a6 = fmaf(wt, bfl(v.w), a6); a7 = fmaf(wt, bfh(v.w), a7);
        }
        if (i1 < s1) {
            int ex = __builtin_nontemporal_load(&sorted[i1].x);
            int ey = __builtin_nontemporal_load(&sorted[i1].y);
            float wt = __int_as_float(ey);
            uint4 v = src[(size_t)ex * 8 + s];
            a0 = fmaf(wt, bfl(v.x), a0); a1 = fmaf(wt, bfh(v.x), a1);
            a2 = fmaf(wt, bfl(v.y), a2); a3 = fmaf(wt, bfh(v.y), a3);
            a4 = fmaf(wt, bfl(v.z), a4); a5 = fmaf(wt, bfh(v.z), a5);
            a6 = fmaf(wt, bfl(v.w), a6); a7 = fmaf(wt, bfh(v.w), a7);
        }
    }

    // reduce across the 8 edge groups (lane bits 3,4,5)
#define RED(m) \
    a0 += __shfl_xor(a0, m); a1 += __shfl_xor(a1, m); \
    a2 += __shfl_xor(a2, m); a3 += __shfl_xor(a3, m); \
    a4 += __shfl_xor(a4, m); a5 += __shfl_xor(a5, m); \
    a6 += __shfl_xor(a6, m); a7 += __shfl_xor(a7, m);
    RED(8) RED(16) RED(32)
#undef RED

    if (WRITE_Y && g == 0) {
        uint4 o;
        o.x = pk(a0, a1); o.y = pk(a2, a3);
        o.z = pk(a4, a5); o.w = pk(a6, a7);
        y[(size_t)r * 8 + s] = o;
    }
    if (g == 1) {
        constexpr float sc = 1.0f / 3.0f;
        size_t ob = (size_t)r * 16 + 2 * s;
        if (FIRST) {
            acc[ob]     = make_float4(a0 * sc, a1 * sc, a2 * sc, a3 * sc);
            acc[ob + 1] = make_float4(a4 * sc, a5 * sc, a6 * sc, a7 * sc);
        } else {
            float4 x0 = acc[ob];
            float4 x1 = acc[ob + 1];
            x0.x += a0 * sc; x0.y += a1 * sc; x0.z += a2 * sc; x0.w += a3 * sc;
            x1.x += a4 * sc; x1.y += a5 * sc; x1.z += a6 * sc; x1.w += a7 * sc;
            acc[ob]     = x0;
            acc[ob + 1] = x1;
        }
    }
}

// ---------------- launch ----------------

extern "C" void kernel_launch(void* const* d_in, const int* in_sizes, int n_in,
                              void* d_out, int out_size, void* d_ws, size_t ws_size,
                              hipStream_t stream) {
    const float* user_emb = (const float*)d_in[0];
    const float* item_emb = (const float*)d_in[1];
    const float* edge_w   = (const float*)d_in[2];
    const int*   edge_row = (const int*)d_in[3];
    const int*   edge_col = (const int*)d_in[4];
    float*       out      = (float*)d_out;

    // ws layout: two bf16 embedding buffers + CSR
    char* p = (char*)d_ws;
    uint4* ebuf = (uint4*)p;        p += (size_t)N_NODES * 8 * sizeof(uint4);   // 25.6 MB
    uint4* ybuf = (uint4*)p;        p += (size_t)N_NODES * 8 * sizeof(uint4);   // 25.6 MB
    int2*  sorted = (int2*)p;       p += (size_t)N_EDGES * sizeof(int2);        // 25.6 MB
    int*   cnt = (int*)p;           p += (size_t)N_NODES * sizeof(int);
    int*   row_start = (int*)p;     p += (size_t)(N_NODES + 1) * sizeof(int);
    int*   cursor = (int*)p;        p += (size_t)N_NODES * sizeof(int);
    int*   partials = (int*)p;      p += (size_t)SCAN_BLOCK * sizeof(int);
    int*   wq = (int*)p;            p += (size_t)NQ * sizeof(int);

    hipMemsetAsync(cnt, 0, (size_t)N_NODES * sizeof(int), stream);
    hipMemsetAsync(wq, 0, (size_t)NQ * sizeof(int), stream);

    concat_bf16<<<(N_NODES * 8 + 255) / 256, 256, 0, stream>>>(
        (const float4*)user_emb, (const float4*)item_emb, ebuf);

    histogram<<<(N_EDGES + 255) / 256, 256, 0, stream>>>(edge_row, cnt);
    scan_reduce<<<NUM_SCAN_BLOCKS, SCAN_BLOCK, 0, stream>>>(cnt, partials);
    scan_partials<<<1, SCAN_BLOCK, 0, stream>>>(partials);
    scan_final<<<NUM_SCAN_BLOCKS, SCAN_BLOCK, 0, stream>>>(cnt, partials, row_start, cursor);
    scatter_win<<<1024, 256, 0, stream>>>(edge_row, edge_col, edge_w, cursor, sorted, wq);

    int grid = (N_NODES + 3) / 4;                  // 4 rows per 256-thread block
    // layer 0: ebuf -> ybuf
    spmm_bf16<true, true><<<grid, 256, 0, stream>>>(row_start, sorted, ebuf, ybuf, (float4*)out);
    // layer 1: ybuf -> ebuf (ebuf dead after layer 0)
    spmm_bf16<false, true><<<grid, 256, 0, stream>>>(row_start, sorted, ybuf, ebuf, (float4*)out);
    // layer 2: ebuf -> acc only
    spmm_bf16<false, false><<<grid, 256, 0, stream>>>(row_start, sorted, ebuf, ybuf, (float4*)out);
}